// Round 5
// baseline (128.236 us; speedup 1.0000x reference)
//
#include <hip/hip_runtime.h>

// AGNNConv on gfx950:
//   Xp = bf16(X @ W)   (MFMA 16x16x32 bf16; B fragments hoisted, rowptr fused)
//   out[r] = sum_e exp(aw*<Xp[r],Xp[c]>)*Xp[c] / sum_e exp(...)
// N=100000, E=1200000, D=64.

typedef __attribute__((ext_vector_type(8))) short short8;
typedef __attribute__((ext_vector_type(4))) float f32x4;

__device__ __forceinline__ unsigned short f2bf(float f) {   // RNE f32->bf16
    unsigned u = __float_as_uint(f);
    return (unsigned short)((u + 0x7fffu + ((u >> 16) & 1u)) >> 16);
}
__device__ __forceinline__ float blo(unsigned u) { return __uint_as_float(u << 16); }
__device__ __forceinline__ float bhi(unsigned u) { return __uint_as_float(u & 0xffff0000u); }

// ---- K1: fused CSR rowptr build + Xp = bf16(X @ W) via MFMA ---------------
// B fragments (W) loaded ONCE per wave; block loops row-tiles grid-stride.
__global__ __launch_bounds__(256) void gemm_rowptr(
    const float* __restrict__ X, const float* __restrict__ W,
    const int* __restrict__ row, unsigned short* __restrict__ Xpb,
    int* __restrict__ rp, int N, int E)
{
    // rowptr: grid-stride over edges (row[] sorted, every row non-empty)
    {
        const int stride = gridDim.x * 256;
        for (int e = blockIdx.x * 256 + threadIdx.x; e < E; e += stride) {
            int r = row[e];
            if (e == 0)                rp[r] = 0;
            else if (row[e - 1] != r)  rp[r] = e;
            if (e == E - 1)            rp[N] = E;
        }
    }

    const int lane = threadIdx.x & 63;
    const int wv   = threadIdx.x >> 6;       // 0..3: col block
    const int m    = lane & 15;              // A-row / B-col / D-col
    const int kb   = (lane >> 4) << 3;       // k-base: 0,8,16,24

    // B fragments: lane holds W[kb + j (+32)][16*wv + m]  (loop-invariant)
    const float* wc = W + (size_t)kb * 64 + 16 * wv + m;
    short8 b0, b1;
#pragma unroll
    for (int j = 0; j < 8; ++j) b0[j] = f2bf(wc[j * 64]);
#pragma unroll
    for (int j = 0; j < 8; ++j) b1[j] = f2bf(wc[(j + 32) * 64]);

    const int ntiles = (N + 15) >> 4;
    for (int t = blockIdx.x; t < ntiles; t += gridDim.x) {
        const int r0 = t << 4;
        const int rA = min(r0 + m, N - 1);               // clamped load row
        const float* xr = X + (size_t)rA * 64 + kb;
        float4 aL0 = *(const float4*)(xr);
        float4 aH0 = *(const float4*)(xr + 4);
        float4 aL1 = *(const float4*)(xr + 32);
        float4 aH1 = *(const float4*)(xr + 36);
        short8 a0, a1;
        a0[0]=f2bf(aL0.x); a0[1]=f2bf(aL0.y); a0[2]=f2bf(aL0.z); a0[3]=f2bf(aL0.w);
        a0[4]=f2bf(aH0.x); a0[5]=f2bf(aH0.y); a0[6]=f2bf(aH0.z); a0[7]=f2bf(aH0.w);
        a1[0]=f2bf(aL1.x); a1[1]=f2bf(aL1.y); a1[2]=f2bf(aL1.z); a1[3]=f2bf(aL1.w);
        a1[4]=f2bf(aH1.x); a1[5]=f2bf(aH1.y); a1[6]=f2bf(aH1.z); a1[7]=f2bf(aH1.w);

        f32x4 acc = {0.f, 0.f, 0.f, 0.f};
        acc = __builtin_amdgcn_mfma_f32_16x16x32_bf16(a0, b0, acc, 0, 0, 0);
        acc = __builtin_amdgcn_mfma_f32_16x16x32_bf16(a1, b1, acc, 0, 0, 0);

        // D: col = 16*wv + m, row = r0 + (lane>>4)*4 + j
        const int rD = r0 + ((lane >> 4) << 2);
        unsigned short* o = Xpb + (size_t)rD * 64 + 16 * wv + m;
#pragma unroll
        for (int j = 0; j < 4; ++j)
            if (rD + j < N) o[j * 64] = f2bf(acc[j]);
    }
}

// ---- K2: aggregation. 4 rows/wave, 16 lanes/row, 4 bf16 features/lane -----
// 16-lane group sum via DPP VALU adds (no LDS pipe, ~30cy chain vs ~160cy
// for 4 chained ds_swizzle round-trips):
//   quad_perm xor1 (0xB1), quad_perm xor2 (0x4E),
//   row_half_mirror (0x141), row_mirror (0x140) — all within the 16-lane row.
#define DPP_ADD(P, CTRL)                                                          \
    P += __int_as_float(__builtin_amdgcn_update_dpp(                              \
        __float_as_int(P), __float_as_int(P), CTRL, 0xf, 0xf, false));

#define AGG_STEP(G, OFF)                                                          \
    {                                                                             \
        float x0 = blo(G.x), x1 = bhi(G.x), x2 = blo(G.y), x3 = bhi(G.y);         \
        float p = x0 * xr0;                                                       \
        p = fmaf(x1, xr1, p);                                                     \
        p = fmaf(x2, xr2, p);                                                     \
        p = fmaf(x3, xr3, p);                                                     \
        DPP_ADD(p, 0xB1)   /* xor1  */                                            \
        DPP_ADD(p, 0x4E)   /* xor2  */                                            \
        DPP_ADD(p, 0x141)  /* xor4  (half mirror) */                              \
        DPP_ADD(p, 0x140)  /* xor8  (row mirror)  */                              \
        float att = exp2f(p * aw2);                                               \
        att = (e + OFF < end) ? att : 0.f;                                        \
        acc0 = fmaf(att, x0, acc0);                                               \
        acc1 = fmaf(att, x1, acc1);                                               \
        acc2 = fmaf(att, x2, acc2);                                               \
        acc3 = fmaf(att, x3, acc3);                                               \
        rs += att;                                                                \
    }

__global__ __launch_bounds__(256) void agg(
    const unsigned short* __restrict__ Xpb, const int* __restrict__ rp,
    const int* __restrict__ col, const float* __restrict__ attw,
    float* __restrict__ out, int N)
{
    const int lane = threadIdx.x & 63;
    const int t    = lane & 15;                                   // pos in group
    const int wid  = (int)((blockIdx.x * blockDim.x + threadIdx.x) >> 6);
    const int r    = (wid << 2) + (lane >> 4);
    if ((wid << 2) >= N) return;
    const int  rr    = (r < N) ? r : (N - 1);
    const bool rowok = (r < N);

    const float aw2   = attw[0] * 1.4426950408889634f;   // fold ln2: exp->exp2
    const int   start = rp[rr];
    const int   end   = rowok ? rp[rr + 1] : start;
    const int   cap   = (end > start) ? (end - 1) : start;        // clamp target

    const char* xb = (const char*)Xpb + (t << 3);                 // lane byte base
    uint2 xw = *(const uint2*)(xb + ((size_t)rr << 7));
    const float xr0 = blo(xw.x), xr1 = bhi(xw.x), xr2 = blo(xw.y), xr3 = bhi(xw.y);

    float acc0 = 0.f, acc1 = 0.f, acc2 = 0.f, acc3 = 0.f, rs = 0.f;

    // ---- pipeline prologue: packets 0 and 1 gathered, packet-2 cols loaded
    int c0 = col[min(start,     cap)];
    int c1 = col[min(start + 1, cap)];
    int c2 = col[min(start + 2, cap)];
    int c3 = col[min(start + 3, cap)];
    uint2 g0 = *(const uint2*)(xb + ((size_t)c0 << 7));
    uint2 g1 = *(const uint2*)(xb + ((size_t)c1 << 7));
    uint2 g2 = *(const uint2*)(xb + ((size_t)c2 << 7));
    uint2 g3 = *(const uint2*)(xb + ((size_t)c3 << 7));
    c0 = col[min(start + 4, cap)];
    c1 = col[min(start + 5, cap)];
    c2 = col[min(start + 6, cap)];
    c3 = col[min(start + 7, cap)];
    uint2 h0 = *(const uint2*)(xb + ((size_t)c0 << 7));
    uint2 h1 = *(const uint2*)(xb + ((size_t)c1 << 7));
    uint2 h2 = *(const uint2*)(xb + ((size_t)c2 << 7));
    uint2 h3 = *(const uint2*)(xb + ((size_t)c3 << 7));
    int n0 = col[min(start +  8, cap)];
    int n1 = col[min(start +  9, cap)];
    int n2 = col[min(start + 10, cap)];
    int n3 = col[min(start + 11, cap)];

    for (int e = start; e < end; e += 4) {
        // issue gathers for packet e+8 (cols resident in n*)
        uint2 G0 = *(const uint2*)(xb + ((size_t)n0 << 7));
        uint2 G1 = *(const uint2*)(xb + ((size_t)n1 << 7));
        uint2 G2 = *(const uint2*)(xb + ((size_t)n2 << 7));
        uint2 G3 = *(const uint2*)(xb + ((size_t)n3 << 7));
        // issue cols for packet e+12
        int m0 = col[min(e + 12, cap)];
        int m1 = col[min(e + 13, cap)];
        int m2 = col[min(e + 14, cap)];
        int m3 = col[min(e + 15, cap)];

        AGG_STEP(g0, 0)
        AGG_STEP(g1, 1)
        AGG_STEP(g2, 2)
        AGG_STEP(g3, 3)

        g0 = h0; g1 = h1; g2 = h2; g3 = h3;
        h0 = G0; h1 = G1; h2 = G2; h3 = G3;
        n0 = m0; n1 = m1; n2 = m2; n3 = m3;
    }

    if (rowok) {
        float inv = 1.0f / rs;
        *(float4*)(out + ((size_t)r << 6) + (t << 2)) =
            make_float4(acc0 * inv, acc1 * inv, acc2 * inv, acc3 * inv);
    }
}

// ---------------------------------------------------------------------------
extern "C" void kernel_launch(void* const* d_in, const int* in_sizes, int n_in,
                              void* d_out, int out_size, void* d_ws, size_t ws_size,
                              hipStream_t stream)
{
    const float* X    = (const float*)d_in[0];
    const float* W    = (const float*)d_in[1];
    const float* attw = (const float*)d_in[2];
    const int*   row  = (const int*)d_in[3];
    const int*   col  = (const int*)d_in[4];
    float*       out  = (float*)d_out;

    const int N = in_sizes[0] / 64;
    const int E = in_sizes[3];

    unsigned short* Xpb = (unsigned short*)d_ws;                       // N*64 bf16
    int* rp = (int*)((char*)d_ws + (size_t)N * 64 * sizeof(unsigned short));

    gemm_rowptr<<<2048, 256, 0, stream>>>(X, W, row, Xpb, rp, N, E);

    int waves = (N + 3) / 4;
    int gb2   = (waves * 64 + 255) / 256;
    agg<<<gb2, 256, 0, stream>>>(Xpb, rp, col, attw, out, N);
}

// Round 6
// 125.053 us; speedup vs baseline: 1.0255x; 1.0255x over previous
//
#include <hip/hip_runtime.h>

// AGNNConv on gfx950:
//   Xp = bf16(X @ W)   (MFMA 16x16x32 bf16; one 16-row tile per WAVE, rowptr fused)
//   out[r] = sum_e exp(aw*<Xp[r],Xp[c]>)*Xp[c] / sum_e exp(...)
// N=100000, E=1200000, D=64.

typedef __attribute__((ext_vector_type(8))) short short8;
typedef __attribute__((ext_vector_type(4))) float f32x4;

__device__ __forceinline__ unsigned short f2bf(float f) {   // RNE f32->bf16
    unsigned u = __float_as_uint(f);
    return (unsigned short)((u + 0x7fffu + ((u >> 16) & 1u)) >> 16);
}
__device__ __forceinline__ float blo(unsigned u) { return __uint_as_float(u << 16); }
__device__ __forceinline__ float bhi(unsigned u) { return __uint_as_float(u & 0xffff0000u); }

// ---- K1: fused CSR rowptr build + Xp = bf16(X @ W) via MFMA ---------------
// One 16-row tile per wave (X read exactly once); each wave holds B fragments
// for all 4 col-blocks (8 MFMAs per tile, K=64).
__global__ __launch_bounds__(256) void gemm_rowptr(
    const float* __restrict__ X, const float* __restrict__ W,
    const int* __restrict__ row, unsigned short* __restrict__ Xpb,
    int* __restrict__ rp, int N, int E)
{
    // rowptr: grid-stride over edges (row[] sorted, every row non-empty)
    {
        const int stride = gridDim.x * 256;
        for (int e = blockIdx.x * 256 + threadIdx.x; e < E; e += stride) {
            int r = row[e];
            if (e == 0)                rp[r] = 0;
            else if (row[e - 1] != r)  rp[r] = e;
            if (e == E - 1)            rp[N] = E;
        }
    }

    const int lane = threadIdx.x & 63;
    const int m    = lane & 15;              // A-row / B-col / D-col
    const int kb   = (lane >> 4) << 3;       // k-base: 0,8,16,24

    // B fragments for all 4 col-blocks: lane holds W[kb + j (+32)][16*cb + m]
    short8 b0[4], b1[4];
#pragma unroll
    for (int cb = 0; cb < 4; ++cb) {
        const float* wc = W + (size_t)kb * 64 + 16 * cb + m;
#pragma unroll
        for (int j = 0; j < 8; ++j) b0[cb][j] = f2bf(wc[j * 64]);
#pragma unroll
        for (int j = 0; j < 8; ++j) b1[cb][j] = f2bf(wc[(j + 32) * 64]);
    }

    const int ntiles = (N + 15) >> 4;
    const int gwaves = gridDim.x << 2;
    for (int t = (blockIdx.x << 2) + (threadIdx.x >> 6); t < ntiles; t += gwaves) {
        const int r0 = t << 4;
        const int rA = min(r0 + m, N - 1);               // clamped load row
        const float* xr = X + (size_t)rA * 64 + kb;
        float4 aL0 = *(const float4*)(xr);
        float4 aH0 = *(const float4*)(xr + 4);
        float4 aL1 = *(const float4*)(xr + 32);
        float4 aH1 = *(const float4*)(xr + 36);
        short8 a0, a1;
        a0[0]=f2bf(aL0.x); a0[1]=f2bf(aL0.y); a0[2]=f2bf(aL0.z); a0[3]=f2bf(aL0.w);
        a0[4]=f2bf(aH0.x); a0[5]=f2bf(aH0.y); a0[6]=f2bf(aH0.z); a0[7]=f2bf(aH0.w);
        a1[0]=f2bf(aL1.x); a1[1]=f2bf(aL1.y); a1[2]=f2bf(aL1.z); a1[3]=f2bf(aL1.w);
        a1[4]=f2bf(aH1.x); a1[5]=f2bf(aH1.y); a1[6]=f2bf(aH1.z); a1[7]=f2bf(aH1.w);

        f32x4 acc0 = {0.f,0.f,0.f,0.f}, acc1 = acc0, acc2 = acc0, acc3 = acc0;
        acc0 = __builtin_amdgcn_mfma_f32_16x16x32_bf16(a0, b0[0], acc0, 0, 0, 0);
        acc1 = __builtin_amdgcn_mfma_f32_16x16x32_bf16(a0, b0[1], acc1, 0, 0, 0);
        acc2 = __builtin_amdgcn_mfma_f32_16x16x32_bf16(a0, b0[2], acc2, 0, 0, 0);
        acc3 = __builtin_amdgcn_mfma_f32_16x16x32_bf16(a0, b0[3], acc3, 0, 0, 0);
        acc0 = __builtin_amdgcn_mfma_f32_16x16x32_bf16(a1, b1[0], acc0, 0, 0, 0);
        acc1 = __builtin_amdgcn_mfma_f32_16x16x32_bf16(a1, b1[1], acc1, 0, 0, 0);
        acc2 = __builtin_amdgcn_mfma_f32_16x16x32_bf16(a1, b1[2], acc2, 0, 0, 0);
        acc3 = __builtin_amdgcn_mfma_f32_16x16x32_bf16(a1, b1[3], acc3, 0, 0, 0);

        // D: col = 16*cb + m, row = r0 + (lane>>4)*4 + j
        const int rD = r0 + ((lane >> 4) << 2);
        unsigned short* o = Xpb + (size_t)rD * 64 + m;
#pragma unroll
        for (int j = 0; j < 4; ++j) {
            if (rD + j < N) {
                o[j * 64 +  0] = f2bf(acc0[j]);
                o[j * 64 + 16] = f2bf(acc1[j]);
                o[j * 64 + 32] = f2bf(acc2[j]);
                o[j * 64 + 48] = f2bf(acc3[j]);
            }
        }
    }
}

// ---- K2: aggregation. 4 rows/wave, 16 lanes/row, 4 bf16 features/lane -----
// Depth-4 packet pipeline: 12 Xp-gathers outstanding; gathers issued 3
// iterations (~750cy) before use to cover L3 latency. Cols (contiguous,
// L2-hot) loaded 1 iteration before gather-issue.
#define DPP_ADD(P, CTRL)                                                          \
    P += __int_as_float(__builtin_amdgcn_update_dpp(                              \
        __float_as_int(P), __float_as_int(P), CTRL, 0xf, 0xf, false));

#define AGG_STEP(G, OFF)                                                          \
    {                                                                             \
        float x0 = blo(G.x), x1 = bhi(G.x), x2 = blo(G.y), x3 = bhi(G.y);         \
        float p = x0 * xr0;                                                       \
        p = fmaf(x1, xr1, p);                                                     \
        p = fmaf(x2, xr2, p);                                                     \
        p = fmaf(x3, xr3, p);                                                     \
        DPP_ADD(p, 0xB1)   /* quad_perm xor1 */                                   \
        DPP_ADD(p, 0x4E)   /* quad_perm xor2 */                                   \
        DPP_ADD(p, 0x141)  /* row_half_mirror = xor4 */                           \
        DPP_ADD(p, 0x140)  /* row_mirror      = xor8 */                           \
        float att = exp2f(p * aw2);                                               \
        att = (e + OFF < end) ? att : 0.f;                                        \
        acc0 = fmaf(att, x0, acc0);                                               \
        acc1 = fmaf(att, x1, acc1);                                               \
        acc2 = fmaf(att, x2, acc2);                                               \
        acc3 = fmaf(att, x3, acc3);                                               \
        rs += att;                                                                \
    }

#define CL(i)  col[min((i), cap)]
#define GX(c)  (*(const uint2*)(xb + ((size_t)(c) << 7)))

__global__ __launch_bounds__(256) void agg(
    const unsigned short* __restrict__ Xpb, const int* __restrict__ rp,
    const int* __restrict__ col, const float* __restrict__ attw,
    float* __restrict__ out, int N)
{
    const int lane = threadIdx.x & 63;
    const int t    = lane & 15;                                   // pos in group
    const int wid  = (int)((blockIdx.x * blockDim.x + threadIdx.x) >> 6);
    const int r    = (wid << 2) + (lane >> 4);
    if ((wid << 2) >= N) return;
    const int  rr    = (r < N) ? r : (N - 1);
    const bool rowok = (r < N);

    const float aw2   = attw[0] * 1.4426950408889634f;   // fold ln2: exp->exp2
    const int   start = rp[rr];
    const int   end   = rowok ? rp[rr + 1] : start;
    const int   cap   = (end > start) ? (end - 1) : start;        // clamp target

    const char* xb = (const char*)Xpb + (t << 3);                 // lane byte base
    uint2 xw = *(const uint2*)(xb + ((size_t)rr << 7));
    const float xr0 = blo(xw.x), xr1 = bhi(xw.x), xr2 = blo(xw.y), xr3 = bhi(xw.y);

    float acc0 = 0.f, acc1 = 0.f, acc2 = 0.f, acc3 = 0.f, rs = 0.f;

    // ---- prologue: packets 0,1,2 gathered; cols for packet 3 resident
    uint2 g0 = GX(CL(start + 0)), g1 = GX(CL(start + 1)),
          g2 = GX(CL(start + 2)), g3 = GX(CL(start + 3));
    uint2 h0 = GX(CL(start + 4)), h1 = GX(CL(start + 5)),
          h2 = GX(CL(start + 6)), h3 = GX(CL(start + 7));
    uint2 i0 = GX(CL(start + 8)), i1 = GX(CL(start + 9)),
          i2 = GX(CL(start +10)), i3 = GX(CL(start +11));
    int n0 = CL(start + 12), n1 = CL(start + 13),
        n2 = CL(start + 14), n3 = CL(start + 15);

    for (int e = start; e < end; e += 4) {
        // issue gathers for packet e+12 (cols already resident in n*)
        uint2 j0 = GX(n0), j1 = GX(n1), j2 = GX(n2), j3 = GX(n3);
        // load cols for packet e+16 (contiguous, L2-hot)
        n0 = CL(e + 16); n1 = CL(e + 17); n2 = CL(e + 18); n3 = CL(e + 19);

        AGG_STEP(g0, 0)
        AGG_STEP(g1, 1)
        AGG_STEP(g2, 2)
        AGG_STEP(g3, 3)

        g0 = h0; g1 = h1; g2 = h2; g3 = h3;
        h0 = i0; h1 = i1; h2 = i2; h3 = i3;
        i0 = j0; i1 = j1; i2 = j2; i3 = j3;
    }

    if (rowok) {
        float inv = 1.0f / rs;
        *(float4*)(out + ((size_t)r << 6) + (t << 2)) =
            make_float4(acc0 * inv, acc1 * inv, acc2 * inv, acc3 * inv);
    }
}

// ---------------------------------------------------------------------------
extern "C" void kernel_launch(void* const* d_in, const int* in_sizes, int n_in,
                              void* d_out, int out_size, void* d_ws, size_t ws_size,
                              hipStream_t stream)
{
    const float* X    = (const float*)d_in[0];
    const float* W    = (const float*)d_in[1];
    const float* attw = (const float*)d_in[2];
    const int*   row  = (const int*)d_in[3];
    const int*   col  = (const int*)d_in[4];
    float*       out  = (float*)d_out;

    const int N = in_sizes[0] / 64;
    const int E = in_sizes[3];

    unsigned short* Xpb = (unsigned short*)d_ws;                       // N*64 bf16
    int* rp = (int*)((char*)d_ws + (size_t)N * 64 * sizeof(unsigned short));

    const int ntiles = (N + 15) >> 4;
    gemm_rowptr<<<(ntiles + 3) / 4, 256, 0, stream>>>(X, W, row, Xpb, rp, N, E);

    int waves = (N + 3) / 4;
    int gb2   = (waves * 64 + 255) / 256;
    agg<<<gb2, 256, 0, stream>>>(Xpb, rp, col, attw, out, N);
}